// Round 8
// baseline (232.305 us; speedup 1.0000x reference)
//
#include <hip/hip_runtime.h>
#include <hip/hip_bf16.h>

typedef unsigned short u16;
typedef __bf16 bf16x8 __attribute__((ext_vector_type(8)));
typedef float f32x4 __attribute__((ext_vector_type(4)));

#define AS1 __attribute__((address_space(1)))
#define AS3 __attribute__((address_space(3)))

__device__ inline void gload_lds16(const void* g, void* l) {
    __builtin_amdgcn_global_load_lds((const AS1 void*)g, (AS3 void*)l, 16, 0, 0);
}

__device__ inline u16 f2bf(float f) {
    __hip_bfloat16 h = __float2bfloat16(f);
    return __builtin_bit_cast(u16, h);
}
__device__ inline float bf2f(unsigned u) {
    return __builtin_bit_cast(float, u << 16);
}

// ---------------------------------------------------------------------------
// fused fp32 -> bf16 convert for x, Wq, Wk, Wv (one launch)
// ---------------------------------------------------------------------------
__global__ __launch_bounds__(256)
void cvt_all(const float4* __restrict__ x,  const float4* __restrict__ wq,
             const float4* __restrict__ wk, const float4* __restrict__ wv,
             u16* __restrict__ xb, u16* __restrict__ Wb) {
    int i = blockIdx.x * 256 + threadIdx.x;
    const float4* src; u16* dst; int off;
    if (i < 2097152)      { src = x;  dst = xb;            off = i; }
    else if (i < 2359296) { src = wq; dst = Wb;            off = i - 2097152; }
    else if (i < 2621440) { src = wk; dst = Wb + 1048576;  off = i - 2359296; }
    else                  { src = wv; dst = Wb + 2097152;  off = i - 2621440; }
    float4 v = src[off];
    uint2 pk;
    pk.x = (unsigned)f2bf(v.x) | ((unsigned)f2bf(v.y) << 16);
    pk.y = (unsigned)f2bf(v.z) | ((unsigned)f2bf(v.w) << 16);
    *(uint2*)(dst + (long long)off * 4) = pk;
}

// ---------------------------------------------------------------------------
// Fused QKV projection, one launch, grid (8,64,3) = 1536 equal blocks.
// z=0: Q[g][o] = x[g]·Wq[o] + bq[o]   (ldC=1024, col bias)
// z=1: K[g][o] = x[g]·Wk[o] + bk[o]
// z=2: Vt[d][g] = Wv[d]·x[g] + bv[d]  (ldC=8192, row bias)
// Unified epilogue (single address/bias pipeline) + launch_bounds(256,5)
// to hold VGPR <= 102 (LDS already caps at 5 blocks/CU).
// 128x128 tile, BK=64, granule-XOR LDS swizzle (rule #21 involution).
// ---------------------------------------------------------------------------
__global__ __launch_bounds__(256, 5)
void proj_qkv(const u16* __restrict__ xb, const u16* __restrict__ Wb,
              u16* __restrict__ QK, u16* __restrict__ Vt,
              const float* __restrict__ bq, const float* __restrict__ bk,
              const float* __restrict__ bv)
{
    constexpr int BK = 64, K = 1024;
    __shared__ __align__(16) u16 shA[128 * BK];
    __shared__ __align__(16) u16 shB[128 * BK];
    const int z = blockIdx.z;
    int row0, col0;
    const u16 *Ab, *Bb;
    if (z < 2) {   // XCD x owns xb row slab
        row0 = (blockIdx.x * 8 + (blockIdx.y & 7)) * 128;
        col0 = (int)(blockIdx.y >> 3) * 128;
        Ab = xb + (long long)row0 * K;
        Bb = Wb + (long long)z * 1048576 + (long long)col0 * K;
    } else {       // XCD x owns xb col slab (same xb rows as z<2)
        col0 = (blockIdx.x * 8 + (blockIdx.y & 7)) * 128;
        row0 = (int)(blockIdx.y >> 3) * 128;
        Ab = Wb + 2097152 + (long long)row0 * K;
        Bb = xb + (long long)col0 * K;
    }
    // unified epilogue parameters
    u16* Cb = (z < 2) ? (QK + (long long)z * 8388608) : Vt;
    const int ldC = (z < 2) ? 1024 : 8192;
    const float* bp = (z == 0) ? bq : ((z == 1) ? bk : bv);

    const int t  = (int)threadIdx.x;
    const int l  = t & 63;
    const int w  = t >> 6;
    const int wr = w >> 1, wc = w & 1;
    const int fr = l & 15, fq = l >> 4;

    f32x4 acc[4][4];
    #pragma unroll
    for (int m = 0; m < 4; ++m)
        #pragma unroll
        for (int n = 0; n < 4; ++n)
            acc[m][n] = (f32x4){0.f, 0.f, 0.f, 0.f};

    int aOff[2][4], bOff[2][4];
    #pragma unroll
    for (int kh = 0; kh < 2; ++kh) {
        const int g = ((kh * 4 + fq) ^ (fr & 7)) * 8;
        #pragma unroll
        for (int m = 0; m < 4; ++m) aOff[kh][m] = (wr * 64 + m * 16 + fr) * 64 + g;
        #pragma unroll
        for (int n = 0; n < 4; ++n) bOff[kh][n] = (wc * 64 + n * 16 + fr) * 64 + g;
    }

    for (int kk = 0; kk < K; kk += BK) {
        if (kk) __syncthreads();
        #pragma unroll
        for (int r = 0; r < 4; ++r) {
            const int s  = t + r * 256;
            const int rw = s >> 3;
            const int g  = (s & 7) ^ (rw & 7);
            gload_lds16(Ab + (long long)rw * K + kk + g * 8, (void*)(shA + s * 8));
            gload_lds16(Bb + (long long)rw * K + kk + g * 8, (void*)(shB + s * 8));
        }
        __syncthreads();
        bf16x8 aF[2][4], bF[2][4];
        #pragma unroll
        for (int kh = 0; kh < 2; ++kh) {
            #pragma unroll
            for (int m = 0; m < 4; ++m) aF[kh][m] = *(const bf16x8*)(shA + aOff[kh][m]);
            #pragma unroll
            for (int n = 0; n < 4; ++n) bF[kh][n] = *(const bf16x8*)(shB + bOff[kh][n]);
        }
        #pragma unroll
        for (int kh = 0; kh < 2; ++kh)
            #pragma unroll
            for (int m = 0; m < 4; ++m)
                #pragma unroll
                for (int n = 0; n < 4; ++n)
                    acc[m][n] = __builtin_amdgcn_mfma_f32_16x16x32_bf16(aF[kh][m], bF[kh][n], acc[m][n], 0, 0, 0);
    }

    // unified epilogue: out[(cm+j)*ldC + cn] = acc + colBias(z<2) + rowBias(z==2)
    #pragma unroll
    for (int n = 0; n < 4; ++n) {
        const int cn = col0 + wc * 64 + n * 16 + fr;
        const float cb = (z < 2) ? bp[cn] : 0.0f;
        #pragma unroll
        for (int m = 0; m < 4; ++m) {
            const int cm = row0 + wr * 64 + m * 16 + fq * 4;
            #pragma unroll
            for (int j = 0; j < 4; ++j) {
                const float rb = (z == 2) ? bp[cm + j] : 0.0f;
                Cb[(long long)(cm + j) * ldC + cn] = f2bf(acc[m][n][j] + cb + rb);
            }
        }
    }
}

// ---------------------------------------------------------------------------
// 128x128-tile bf16 GEMM (B^T layout), BK=64, granule-XOR LDS swizzle.
// MODE 1: scores (bf16 out *scale, causal block skip; XCD = batch)
// MODE 2: pv     (f32 out, K-loop = row0+128; XCD = batch; heavy-first)
// ---------------------------------------------------------------------------
template<int MODE>
__global__ __launch_bounds__(256)
void gemm_bt(const u16* __restrict__ A, long long strideAb,
             const u16* __restrict__ Bt, long long strideBb,
             void* __restrict__ Cv, long long strideCb,
             int K, int strideBrow, float scale)
{
    constexpr int BK = 64;
    __shared__ __align__(16) u16 shA[128 * BK];
    __shared__ __align__(16) u16 shB[128 * BK];
    int bz, row0, col0;
    if (MODE == 1) {            // grid (8,8,8): XCD = batch
        bz   = blockIdx.x;
        row0 = blockIdx.y * 128;
        col0 = blockIdx.z * 128;
    } else {                    // MODE 2, heavy rows first
        bz   = blockIdx.x;
        row0 = (7 - (int)blockIdx.y) * 128;
        col0 = blockIdx.z * 128;
    }
    if (MODE == 1 && col0 > row0) return;   // fully-masked causal block
    const u16* Ab = A  + bz * strideAb + (long long)row0 * K;
    const u16* Bb = Bt + bz * strideBb + (long long)col0 * strideBrow;
    int kEnd = K;
    if (MODE == 2) kEnd = row0 + 128;

    const int t  = (int)threadIdx.x;
    const int l  = t & 63;
    const int w  = t >> 6;
    const int wr = w >> 1, wc = w & 1;
    const int fr = l & 15, fq = l >> 4;

    f32x4 acc[4][4];
    #pragma unroll
    for (int m = 0; m < 4; ++m)
        #pragma unroll
        for (int n = 0; n < 4; ++n)
            acc[m][n] = (f32x4){0.f, 0.f, 0.f, 0.f};

    int aOff[2][4], bOff[2][4];
    #pragma unroll
    for (int kh = 0; kh < 2; ++kh) {
        const int g = ((kh * 4 + fq) ^ (fr & 7)) * 8;
        #pragma unroll
        for (int m = 0; m < 4; ++m) aOff[kh][m] = (wr * 64 + m * 16 + fr) * 64 + g;
        #pragma unroll
        for (int n = 0; n < 4; ++n) bOff[kh][n] = (wc * 64 + n * 16 + fr) * 64 + g;
    }

    for (int kk = 0; kk < kEnd; kk += BK) {
        if (kk) __syncthreads();
        #pragma unroll
        for (int r = 0; r < 4; ++r) {
            const int s  = t + r * 256;
            const int rw = s >> 3;
            const int g  = (s & 7) ^ (rw & 7);
            gload_lds16(Ab + (long long)rw * K + kk + g * 8, (void*)(shA + s * 8));
            gload_lds16(Bb + (long long)rw * strideBrow + kk + g * 8, (void*)(shB + s * 8));
        }
        __syncthreads();
        bf16x8 aF[2][4], bF[2][4];
        #pragma unroll
        for (int kh = 0; kh < 2; ++kh) {
            #pragma unroll
            for (int m = 0; m < 4; ++m) aF[kh][m] = *(const bf16x8*)(shA + aOff[kh][m]);
            #pragma unroll
            for (int n = 0; n < 4; ++n) bF[kh][n] = *(const bf16x8*)(shB + bOff[kh][n]);
        }
        #pragma unroll
        for (int kh = 0; kh < 2; ++kh)
            #pragma unroll
            for (int m = 0; m < 4; ++m)
                #pragma unroll
                for (int n = 0; n < 4; ++n)
                    acc[m][n] = __builtin_amdgcn_mfma_f32_16x16x32_bf16(aF[kh][m], bF[kh][n], acc[m][n], 0, 0, 0);
    }

    if (MODE == 1) {
        u16* C = (u16*)Cv + bz * strideCb;
        #pragma unroll
        for (int n = 0; n < 4; ++n) {
            const int cn = col0 + wc * 64 + n * 16 + fr;
            #pragma unroll
            for (int m = 0; m < 4; ++m) {
                const int cm = row0 + wr * 64 + m * 16 + fq * 4;
                #pragma unroll
                for (int j = 0; j < 4; ++j)
                    C[(long long)(cm + j) * 1024 + cn] = f2bf(acc[m][n][j] * scale);
            }
        }
    } else {
        float* C = (float*)Cv + bz * strideCb;
        #pragma unroll
        for (int n = 0; n < 4; ++n) {
            const int cn = col0 + wc * 64 + n * 16 + fr;
            #pragma unroll
            for (int m = 0; m < 4; ++m) {
                const int cm = row0 + wr * 64 + m * 16 + fq * 4;
                #pragma unroll
                for (int j = 0; j < 4; ++j)
                    C[(long long)(cm + j) * 1024 + cn] = acc[m][n][j];
            }
        }
    }
}

// ---------------------------------------------------------------------------
// causal row softmax on bf16 scores: P[row][j] = softmax(S[row][0..q]), 0 j>q.
// Writes only j < ((q>>7)+1)*128 — exactly what PV's causal K-loop reads.
// ---------------------------------------------------------------------------
__global__ __launch_bounds__(256)
void softmax_causal(const u16* __restrict__ S, u16* __restrict__ P) {
    __shared__ float redM[4], redS[4];
    const int row = blockIdx.x;
    const int q   = row & 1023;
    const int t   = (int)threadIdx.x;
    const int l   = t & 63, w = t >> 6;
    const int j0  = t * 4;
    float x0 = -1e30f, x1 = -1e30f, x2 = -1e30f, x3 = -1e30f;
    if (j0 <= q) {
        uint2 raw = *(const uint2*)(S + (long long)row * 1024 + j0);
        x0 = bf2f(raw.x & 0xffffu);
        x1 = (j0 + 1 <= q) ? bf2f(raw.x >> 16) : -1e30f;
        x2 = (j0 + 2 <= q) ? bf2f(raw.y & 0xffffu) : -1e30f;
        x3 = (j0 + 3 <= q) ? bf2f(raw.y >> 16) : -1e30f;
    }
    float m = fmaxf(fmaxf(x0, x1), fmaxf(x2, x3));
    #pragma unroll
    for (int o = 32; o > 0; o >>= 1) m = fmaxf(m, __shfl_xor(m, o, 64));
    if (l == 0) redM[w] = m;
    __syncthreads();
    m = fmaxf(fmaxf(redM[0], redM[1]), fmaxf(redM[2], redM[3]));
    float e0 = __expf(x0 - m);
    float e1 = __expf(x1 - m);
    float e2 = __expf(x2 - m);
    float e3 = __expf(x3 - m);
    float s = e0 + e1 + e2 + e3;
    #pragma unroll
    for (int o = 32; o > 0; o >>= 1) s += __shfl_xor(s, o, 64);
    if (l == 0) redS[w] = s;
    __syncthreads();
    s = redS[0] + redS[1] + redS[2] + redS[3];
    const float inv = 1.0f / s;
    const int jmax = ((q >> 7) + 1) << 7;   // padded causal boundary
    if (j0 < jmax) {
        uint2 pk;
        pk.x = (unsigned)f2bf(e0 * inv) | ((unsigned)f2bf(e1 * inv) << 16);
        pk.y = (unsigned)f2bf(e2 * inv) | ((unsigned)f2bf(e3 * inv) << 16);
        *(uint2*)(P + (long long)row * 1024 + j0) = pk;
    }
}

// ---------------------------------------------------------------------------
extern "C" void kernel_launch(void* const* d_in, const int* in_sizes, int n_in,
                              void* d_out, int out_size, void* d_ws, size_t ws_size,
                              hipStream_t stream) {
    const float* x  = (const float*)d_in[0];
    const float* Wq = (const float*)d_in[1];
    const float* bq = (const float*)d_in[2];
    const float* Wk = (const float*)d_in[3];
    const float* bk = (const float*)d_in[4];
    const float* Wv = (const float*)d_in[5];
    const float* bv = (const float*)d_in[6];
    float* out = (float*)d_out;
    char* ws = (char*)d_ws;

    // workspace layout (102 MB)
    u16* xb  = (u16*)(ws + 0);                      // 16 MB [8192][1024]
    u16* Wb  = (u16*)(ws + ((size_t)16 << 20));     //  6 MB [3][1024][1024]
    u16* QK  = (u16*)(ws + ((size_t)22 << 20));     // 32 MB [2][8192][1024]
    u16* Vt  = (u16*)(ws + ((size_t)54 << 20));     // 16 MB [1024][8192] (d, b*1024+k)
    u16* SC  = (u16*)(ws + ((size_t)70 << 20));     // 16 MB [8][1024][1024] bf16
    u16* P   = (u16*)(ws + ((size_t)86 << 20));     // 16 MB [8][1024][1024] bf16

    // 1) convert inputs to bf16 (single launch)
    cvt_all<<<11264, 256, 0, stream>>>((const float4*)x, (const float4*)Wq,
                                       (const float4*)Wk, (const float4*)Wv, xb, Wb);

    // 2) fused Q,K,Vt projections — 1536 equal blocks
    proj_qkv<<<dim3(8, 64, 3), 256, 0, stream>>>(xb, Wb, QK, Vt, bq, bk, bv);

    // 3) scores = Q K^T / 32 (bf16 out, causal block skip; XCD = batch)
    gemm_bt<1><<<dim3(8, 8, 8), 256, 0, stream>>>(QK, 1048576LL, QK + 8388608LL, 1048576LL,
                                                  SC, 1048576LL, 1024, 1024, 0.03125f);

    // 4) causal softmax -> P (bf16)
    softmax_causal<<<8192, 256, 0, stream>>>(SC, P);

    // 5) O = P V  (B-tile = Vt rows d, row-stride 8192, batch offset 1024)
    gemm_bt<2><<<dim3(8, 8, 8), 256, 0, stream>>>(P, 1048576LL, Vt, 1024LL, out, 1048576LL,
                                                  1024, 8192, 1.0f);
}

// Round 9
// 113.954 us; speedup vs baseline: 2.0386x; 2.0386x over previous
//
#include <hip/hip_runtime.h>
#include <hip/hip_bf16.h>

typedef unsigned short u16;
typedef __bf16 bf16x8 __attribute__((ext_vector_type(8)));
typedef float f32x4 __attribute__((ext_vector_type(4)));

#define AS1 __attribute__((address_space(1)))
#define AS3 __attribute__((address_space(3)))

__device__ inline void gload_lds16(const void* g, void* l) {
    __builtin_amdgcn_global_load_lds((const AS1 void*)g, (AS3 void*)l, 16, 0, 0);
}

__device__ inline u16 f2bf(float f) {
    __hip_bfloat16 h = __float2bfloat16(f);
    return __builtin_bit_cast(u16, h);
}
__device__ inline float bf2f(unsigned u) {
    return __builtin_bit_cast(float, u << 16);
}

// ---------------------------------------------------------------------------
// fused fp32 -> bf16 convert for x, Wq, Wk, Wv (one launch)
// ---------------------------------------------------------------------------
__global__ __launch_bounds__(256)
void cvt_all(const float4* __restrict__ x,  const float4* __restrict__ wq,
             const float4* __restrict__ wk, const float4* __restrict__ wv,
             u16* __restrict__ xb, u16* __restrict__ Wb) {
    int i = blockIdx.x * 256 + threadIdx.x;
    const float4* src; u16* dst; int off;
    if (i < 2097152)      { src = x;  dst = xb;            off = i; }
    else if (i < 2359296) { src = wq; dst = Wb;            off = i - 2097152; }
    else if (i < 2621440) { src = wk; dst = Wb + 1048576;  off = i - 2359296; }
    else                  { src = wv; dst = Wb + 2097152;  off = i - 2621440; }
    float4 v = src[off];
    uint2 pk;
    pk.x = (unsigned)f2bf(v.x) | ((unsigned)f2bf(v.y) << 16);
    pk.y = (unsigned)f2bf(v.z) | ((unsigned)f2bf(v.w) << 16);
    *(uint2*)(dst + (long long)off * 4) = pk;
}

// ---------------------------------------------------------------------------
// Fused QKV projection, one launch, grid (8,64,3) = 1536 equal blocks.
// z=0: Q[g][o]  = x[g]·Wq[o] + bq[o]   (ldC=1024, col bias)
// z=1: K[g][o]  = x[g]·Wk[o] + bk[o]
// z=2: Vt[d][g] = Wv[d]·x[g]           (ldC=8192, NO bias — bv is added in
//                 PV's epilogue: O = P·V0 + bv since sum_k P[q][k] == 1)
// Single uniform epilogue path keeps VGPR low (no launch_bounds games —
// round-8 lesson: forcing occupancy caused a 48-VGPR spill catastrophe).
// 128x128 tile, BK=64, granule-XOR LDS swizzle (rule #21 involution).
// ---------------------------------------------------------------------------
__global__ __launch_bounds__(256)
void proj_qkv(const u16* __restrict__ xb, const u16* __restrict__ Wb,
              u16* __restrict__ QK, u16* __restrict__ Vt,
              const float* __restrict__ bq, const float* __restrict__ bk)
{
    constexpr int BK = 64, K = 1024;
    __shared__ __align__(16) u16 shA[128 * BK];
    __shared__ __align__(16) u16 shB[128 * BK];
    const int z = blockIdx.z;
    int row0, col0;
    const u16 *Ab, *Bb;
    if (z < 2) {   // XCD x owns xb row slab
        row0 = (blockIdx.x * 8 + (blockIdx.y & 7)) * 128;
        col0 = (int)(blockIdx.y >> 3) * 128;
        Ab = xb + (long long)row0 * K;
        Bb = Wb + (long long)z * 1048576 + (long long)col0 * K;
    } else {       // XCD x owns xb col slab (same xb rows as z<2)
        col0 = (blockIdx.x * 8 + (blockIdx.y & 7)) * 128;
        row0 = (int)(blockIdx.y >> 3) * 128;
        Ab = Wb + 2097152 + (long long)row0 * K;
        Bb = xb + (long long)col0 * K;
    }
    u16* Cb = (z < 2) ? (QK + (long long)z * 8388608) : Vt;
    const int ldC = (z < 2) ? 1024 : 8192;
    const float* bp = (z == 1) ? bk : bq;   // only read when z<2

    const int t  = (int)threadIdx.x;
    const int l  = t & 63;
    const int w  = t >> 6;
    const int wr = w >> 1, wc = w & 1;
    const int fr = l & 15, fq = l >> 4;

    f32x4 acc[4][4];
    #pragma unroll
    for (int m = 0; m < 4; ++m)
        #pragma unroll
        for (int n = 0; n < 4; ++n)
            acc[m][n] = (f32x4){0.f, 0.f, 0.f, 0.f};

    int aOff[2][4], bOff[2][4];
    #pragma unroll
    for (int kh = 0; kh < 2; ++kh) {
        const int g = ((kh * 4 + fq) ^ (fr & 7)) * 8;
        #pragma unroll
        for (int m = 0; m < 4; ++m) aOff[kh][m] = (wr * 64 + m * 16 + fr) * 64 + g;
        #pragma unroll
        for (int n = 0; n < 4; ++n) bOff[kh][n] = (wc * 64 + n * 16 + fr) * 64 + g;
    }

    for (int kk = 0; kk < K; kk += BK) {
        if (kk) __syncthreads();
        #pragma unroll
        for (int r = 0; r < 4; ++r) {
            const int s  = t + r * 256;
            const int rw = s >> 3;
            const int g  = (s & 7) ^ (rw & 7);
            gload_lds16(Ab + (long long)rw * K + kk + g * 8, (void*)(shA + s * 8));
            gload_lds16(Bb + (long long)rw * K + kk + g * 8, (void*)(shB + s * 8));
        }
        __syncthreads();
        bf16x8 aF[2][4], bF[2][4];
        #pragma unroll
        for (int kh = 0; kh < 2; ++kh) {
            #pragma unroll
            for (int m = 0; m < 4; ++m) aF[kh][m] = *(const bf16x8*)(shA + aOff[kh][m]);
            #pragma unroll
            for (int n = 0; n < 4; ++n) bF[kh][n] = *(const bf16x8*)(shB + bOff[kh][n]);
        }
        #pragma unroll
        for (int kh = 0; kh < 2; ++kh)
            #pragma unroll
            for (int m = 0; m < 4; ++m)
                #pragma unroll
                for (int n = 0; n < 4; ++n)
                    acc[m][n] = __builtin_amdgcn_mfma_f32_16x16x32_bf16(aF[kh][m], bF[kh][n], acc[m][n], 0, 0, 0);
    }

    // uniform epilogue: out[(cm+j)*ldC + cn] = acc + colBias (0 for z==2)
    #pragma unroll
    for (int n = 0; n < 4; ++n) {
        const int cn = col0 + wc * 64 + n * 16 + fr;
        const float cb = (z < 2) ? bp[cn] : 0.0f;
        #pragma unroll
        for (int m = 0; m < 4; ++m) {
            const int cm = row0 + wr * 64 + m * 16 + fq * 4;
            #pragma unroll
            for (int j = 0; j < 4; ++j)
                Cb[(long long)(cm + j) * ldC + cn] = f2bf(acc[m][n][j] + cb);
        }
    }
}

// ---------------------------------------------------------------------------
// 128x128-tile bf16 GEMM (B^T layout), BK=64, granule-XOR LDS swizzle.
// MODE 1: scores (bf16 out *scale, causal block skip; XCD = batch)
// MODE 2: pv     (f32 out + col bias bv, K-loop = row0+128; heavy-first)
// ---------------------------------------------------------------------------
template<int MODE>
__global__ __launch_bounds__(256)
void gemm_bt(const u16* __restrict__ A, long long strideAb,
             const u16* __restrict__ Bt, long long strideBb,
             void* __restrict__ Cv, long long strideCb,
             const float* __restrict__ bias,
             int K, int strideBrow, float scale)
{
    constexpr int BK = 64;
    __shared__ __align__(16) u16 shA[128 * BK];
    __shared__ __align__(16) u16 shB[128 * BK];
    int bz, row0, col0;
    if (MODE == 1) {            // grid (8,8,8): XCD = batch
        bz   = blockIdx.x;
        row0 = blockIdx.y * 128;
        col0 = blockIdx.z * 128;
    } else {                    // MODE 2, heavy rows first
        bz   = blockIdx.x;
        row0 = (7 - (int)blockIdx.y) * 128;
        col0 = blockIdx.z * 128;
    }
    if (MODE == 1 && col0 > row0) return;   // fully-masked causal block
    const u16* Ab = A  + bz * strideAb + (long long)row0 * K;
    const u16* Bb = Bt + bz * strideBb + (long long)col0 * strideBrow;
    int kEnd = K;
    if (MODE == 2) kEnd = row0 + 128;

    const int t  = (int)threadIdx.x;
    const int l  = t & 63;
    const int w  = t >> 6;
    const int wr = w >> 1, wc = w & 1;
    const int fr = l & 15, fq = l >> 4;

    f32x4 acc[4][4];
    #pragma unroll
    for (int m = 0; m < 4; ++m)
        #pragma unroll
        for (int n = 0; n < 4; ++n)
            acc[m][n] = (f32x4){0.f, 0.f, 0.f, 0.f};

    int aOff[2][4], bOff[2][4];
    #pragma unroll
    for (int kh = 0; kh < 2; ++kh) {
        const int g = ((kh * 4 + fq) ^ (fr & 7)) * 8;
        #pragma unroll
        for (int m = 0; m < 4; ++m) aOff[kh][m] = (wr * 64 + m * 16 + fr) * 64 + g;
        #pragma unroll
        for (int n = 0; n < 4; ++n) bOff[kh][n] = (wc * 64 + n * 16 + fr) * 64 + g;
    }

    for (int kk = 0; kk < kEnd; kk += BK) {
        if (kk) __syncthreads();
        #pragma unroll
        for (int r = 0; r < 4; ++r) {
            const int s  = t + r * 256;
            const int rw = s >> 3;
            const int g  = (s & 7) ^ (rw & 7);
            gload_lds16(Ab + (long long)rw * K + kk + g * 8, (void*)(shA + s * 8));
            gload_lds16(Bb + (long long)rw * strideBrow + kk + g * 8, (void*)(shB + s * 8));
        }
        __syncthreads();
        bf16x8 aF[2][4], bF[2][4];
        #pragma unroll
        for (int kh = 0; kh < 2; ++kh) {
            #pragma unroll
            for (int m = 0; m < 4; ++m) aF[kh][m] = *(const bf16x8*)(shA + aOff[kh][m]);
            #pragma unroll
            for (int n = 0; n < 4; ++n) bF[kh][n] = *(const bf16x8*)(shB + bOff[kh][n]);
        }
        #pragma unroll
        for (int kh = 0; kh < 2; ++kh)
            #pragma unroll
            for (int m = 0; m < 4; ++m)
                #pragma unroll
                for (int n = 0; n < 4; ++n)
                    acc[m][n] = __builtin_amdgcn_mfma_f32_16x16x32_bf16(aF[kh][m], bF[kh][n], acc[m][n], 0, 0, 0);
    }

    if (MODE == 1) {
        u16* C = (u16*)Cv + bz * strideCb;
        #pragma unroll
        for (int n = 0; n < 4; ++n) {
            const int cn = col0 + wc * 64 + n * 16 + fr;
            #pragma unroll
            for (int m = 0; m < 4; ++m) {
                const int cm = row0 + wr * 64 + m * 16 + fq * 4;
                #pragma unroll
                for (int j = 0; j < 4; ++j)
                    C[(long long)(cm + j) * 1024 + cn] = f2bf(acc[m][n][j] * scale);
            }
        }
    } else {
        float* C = (float*)Cv + bz * strideCb;
        #pragma unroll
        for (int n = 0; n < 4; ++n) {
            const int cn = col0 + wc * 64 + n * 16 + fr;
            const float bvv = bias[cn];   // V-projection bias folded in here
            #pragma unroll
            for (int m = 0; m < 4; ++m) {
                const int cm = row0 + wr * 64 + m * 16 + fq * 4;
                #pragma unroll
                for (int j = 0; j < 4; ++j)
                    C[(long long)(cm + j) * 1024 + cn] = acc[m][n][j] + bvv;
            }
        }
    }
}

// ---------------------------------------------------------------------------
// causal row softmax on bf16 scores: P[row][j] = softmax(S[row][0..q]), 0 j>q.
// Writes only j < ((q>>7)+1)*128 — exactly what PV's causal K-loop reads.
// ---------------------------------------------------------------------------
__global__ __launch_bounds__(256)
void softmax_causal(const u16* __restrict__ S, u16* __restrict__ P) {
    __shared__ float redM[4], redS[4];
    const int row = blockIdx.x;
    const int q   = row & 1023;
    const int t   = (int)threadIdx.x;
    const int l   = t & 63, w = t >> 6;
    const int j0  = t * 4;
    float x0 = -1e30f, x1 = -1e30f, x2 = -1e30f, x3 = -1e30f;
    if (j0 <= q) {
        uint2 raw = *(const uint2*)(S + (long long)row * 1024 + j0);
        x0 = bf2f(raw.x & 0xffffu);
        x1 = (j0 + 1 <= q) ? bf2f(raw.x >> 16) : -1e30f;
        x2 = (j0 + 2 <= q) ? bf2f(raw.y & 0xffffu) : -1e30f;
        x3 = (j0 + 3 <= q) ? bf2f(raw.y >> 16) : -1e30f;
    }
    float m = fmaxf(fmaxf(x0, x1), fmaxf(x2, x3));
    #pragma unroll
    for (int o = 32; o > 0; o >>= 1) m = fmaxf(m, __shfl_xor(m, o, 64));
    if (l == 0) redM[w] = m;
    __syncthreads();
    m = fmaxf(fmaxf(redM[0], redM[1]), fmaxf(redM[2], redM[3]));
    float e0 = __expf(x0 - m);
    float e1 = __expf(x1 - m);
    float e2 = __expf(x2 - m);
    float e3 = __expf(x3 - m);
    float s = e0 + e1 + e2 + e3;
    #pragma unroll
    for (int o = 32; o > 0; o >>= 1) s += __shfl_xor(s, o, 64);
    if (l == 0) redS[w] = s;
    __syncthreads();
    s = redS[0] + redS[1] + redS[2] + redS[3];
    const float inv = 1.0f / s;
    const int jmax = ((q >> 7) + 1) << 7;   // padded causal boundary
    if (j0 < jmax) {
        uint2 pk;
        pk.x = (unsigned)f2bf(e0 * inv) | ((unsigned)f2bf(e1 * inv) << 16);
        pk.y = (unsigned)f2bf(e2 * inv) | ((unsigned)f2bf(e3 * inv) << 16);
        *(uint2*)(P + (long long)row * 1024 + j0) = pk;
    }
}

// ---------------------------------------------------------------------------
extern "C" void kernel_launch(void* const* d_in, const int* in_sizes, int n_in,
                              void* d_out, int out_size, void* d_ws, size_t ws_size,
                              hipStream_t stream) {
    const float* x  = (const float*)d_in[0];
    const float* Wq = (const float*)d_in[1];
    const float* bq = (const float*)d_in[2];
    const float* Wk = (const float*)d_in[3];
    const float* bk = (const float*)d_in[4];
    const float* Wv = (const float*)d_in[5];
    const float* bv = (const float*)d_in[6];
    float* out = (float*)d_out;
    char* ws = (char*)d_ws;

    // workspace layout (102 MB)
    u16* xb  = (u16*)(ws + 0);                      // 16 MB [8192][1024]
    u16* Wb  = (u16*)(ws + ((size_t)16 << 20));     //  6 MB [3][1024][1024]
    u16* QK  = (u16*)(ws + ((size_t)22 << 20));     // 32 MB [2][8192][1024]
    u16* Vt  = (u16*)(ws + ((size_t)54 << 20));     // 16 MB [1024][8192] (d, b*1024+k)
    u16* SC  = (u16*)(ws + ((size_t)70 << 20));     // 16 MB [8][1024][1024] bf16
    u16* P   = (u16*)(ws + ((size_t)86 << 20));     // 16 MB [8][1024][1024] bf16

    // 1) convert inputs to bf16 (single launch)
    cvt_all<<<11264, 256, 0, stream>>>((const float4*)x, (const float4*)Wq,
                                       (const float4*)Wk, (const float4*)Wv, xb, Wb);

    // 2) fused Q,K,Vt projections — 1536 equal blocks (bv folded into PV)
    proj_qkv<<<dim3(8, 64, 3), 256, 0, stream>>>(xb, Wb, QK, Vt, bq, bk);

    // 3) scores = Q K^T / 32 (bf16 out, causal block skip; XCD = batch)
    gemm_bt<1><<<dim3(8, 8, 8), 256, 0, stream>>>(QK, 1048576LL, QK + 8388608LL, 1048576LL,
                                                  SC, 1048576LL, nullptr,
                                                  1024, 1024, 0.03125f);

    // 4) causal softmax -> P (bf16)
    softmax_causal<<<8192, 256, 0, stream>>>(SC, P);

    // 5) O = P V + bv  (B-tile = Vt rows d, row-stride 8192, batch offset 1024)
    gemm_bt<2><<<dim3(8, 8, 8), 256, 0, stream>>>(P, 1048576LL, Vt, 1024LL, out, 1048576LL,
                                                  bv, 1024, 8192, 1.0f);
}